// Round 1
// baseline (1444.131 us; speedup 1.0000x reference)
//
#include <hip/hip_runtime.h>
#include <hip/hip_bf16.h>

typedef __bf16 bf16;
typedef __bf16 bf16x8 __attribute__((ext_vector_type(8)));
typedef float f32x4 __attribute__((ext_vector_type(4)));

#define D_MODEL 2048
#define D_INNER 4096
#define ROWS    8192   // B*T

__device__ __forceinline__ void gload_lds16(const void* g, void* l) {
    __builtin_amdgcn_global_load_lds(
        (const __attribute__((address_space(1))) void*)g,
        (__attribute__((address_space(3))) void*)l, 16, 0, 0);
}

// ---------------- fp32 -> bf16 weight convert ----------------
__global__ __launch_bounds__(256) void f2b_kernel(const float* __restrict__ in,
                                                  bf16* __restrict__ out, int n8) {
    int i = blockIdx.x * 256 + threadIdx.x;
    if (i >= n8) return;
    long base = (long)i * 8;
    float4 a = *(const float4*)(in + base);
    float4 b = *(const float4*)(in + base + 4);
    bf16x8 o;
    o[0] = (bf16)a.x; o[1] = (bf16)a.y; o[2] = (bf16)a.z; o[3] = (bf16)a.w;
    o[4] = (bf16)b.x; o[5] = (bf16)b.y; o[6] = (bf16)b.z; o[7] = (bf16)b.w;
    *(bf16x8*)(out + base) = o;
}

// ---------------- rmsnorm (F.normalize * sqrt(D)) fp32 -> bf16 ----------------
__global__ __launch_bounds__(256) void rmsnorm_kernel(const float* __restrict__ x,
                                                      bf16* __restrict__ h) {
    const long row = blockIdx.x;
    const float* xr = x + row * D_MODEL;
    float4 v0 = ((const float4*)xr)[threadIdx.x * 2];
    float4 v1 = ((const float4*)xr)[threadIdx.x * 2 + 1];
    float ss = v0.x*v0.x + v0.y*v0.y + v0.z*v0.z + v0.w*v0.w
             + v1.x*v1.x + v1.y*v1.y + v1.z*v1.z + v1.w*v1.w;
    #pragma unroll
    for (int o = 32; o; o >>= 1) ss += __shfl_xor(ss, o, 64);
    __shared__ float red[4];
    if ((threadIdx.x & 63) == 0) red[threadIdx.x >> 6] = ss;
    __syncthreads();
    float tot = red[0] + red[1] + red[2] + red[3];
    float scale = 45.254834f / fmaxf(sqrtf(tot), 1e-12f);  // sqrt(2048)/max(||x||,eps)
    bf16x8 o;
    o[0] = (bf16)(v0.x*scale); o[1] = (bf16)(v0.y*scale);
    o[2] = (bf16)(v0.z*scale); o[3] = (bf16)(v0.w*scale);
    o[4] = (bf16)(v1.x*scale); o[5] = (bf16)(v1.y*scale);
    o[6] = (bf16)(v1.z*scale); o[7] = (bf16)(v1.w*scale);
    *(bf16x8*)(h + row * D_MODEL + threadIdx.x * 8) = o;
}

// ---------------- depthwise causal conv (4 taps) + SiLU gate ----------------
// reads xz = [xp | z] (ROWS x 8192 bf16); writes y in place over the z half
__global__ __launch_bounds__(256) void conv_gate_kernel(bf16* __restrict__ xz,
                                                        const float* __restrict__ cw,
                                                        const float* __restrict__ cb) {
    const int idx = blockIdx.x * 256 + threadIdx.x;   // ROWS*512 threads
    const int c8  = idx & 511;
    const int row = idx >> 9;
    const int t   = row & 2047;                        // position within batch (T=2048)
    const int c0  = c8 * 8;
    float acc[8];
    float wv[8][4];
    #pragma unroll
    for (int e = 0; e < 8; ++e) {
        float4 f = ((const float4*)cw)[c0 + e];
        wv[e][0] = f.x; wv[e][1] = f.y; wv[e][2] = f.z; wv[e][3] = f.w;
        acc[e] = cb[c0 + e];
    }
    #pragma unroll
    for (int j = 0; j < 4; ++j) {
        if (t + j - 3 >= 0) {
            bf16x8 xv = *(const bf16x8*)(xz + (long)(row + j - 3) * (2*D_INNER) + c0);
            #pragma unroll
            for (int e = 0; e < 8; ++e) acc[e] += (float)xv[e] * wv[e][j];
        }
    }
    bf16* zp = xz + (long)row * (2*D_INNER) + D_INNER + c0;
    bf16x8 zv = *(const bf16x8*)zp;
    bf16x8 yv;
    #pragma unroll
    for (int e = 0; e < 8; ++e) {
        float xc = acc[e];
        float s1 = xc / (1.f + __expf(-xc));
        float z  = (float)zv[e];
        float s2 = z / (1.f + __expf(-z));
        yv[e] = (bf16)(s1 * s2);
    }
    *(bf16x8*)zp = yv;
}

// ---------------- bf16 GEMM, C = A @ B^T (+ epilogue) ----------------
// A: MxK (row stride lda), B: NxK row-major (weights), 128x128 tile, BK=32,
// 4 waves (2x2), each wave 64x64 via 4x4 mfma_f32_16x16x32_bf16 fragments.
// EPI: 0 = store bf16, 1 = relu+store bf16, 2 = fp32 res-add + store fp32
template<int EPI>
__global__ __launch_bounds__(256, 2) void gemm_bt(
        const bf16* __restrict__ A, long lda,
        const bf16* __restrict__ B,
        void* __restrict__ C, const float* __restrict__ res,
        int N, int K) {
    __shared__ __align__(16) bf16 As[2][128*32];
    __shared__ __align__(16) bf16 Bs[2][128*32];
    const int wave = threadIdx.x >> 6;
    const int lane = threadIdx.x & 63;
    const int wr = (wave >> 1) * 64;        // wave row offset in tile
    const int wc = (wave & 1) * 64;         // wave col offset in tile
    const int lr = lane & 15;
    const int lk = (lane >> 4) * 8;
    const long rowBase = (long)blockIdx.y * 128;
    const long colBase = (long)blockIdx.x * 128;
    const bf16* Abase = A + rowBase * lda;
    const bf16* Bbase = B + colBase * (long)K;

    // staging: 2 issues x 4 waves x 64 lanes x 16B = 8192B = one 128x32 bf16 tile
    const int se = wave * 512 + lane * 8;   // per-lane element offset (issue 0)
    const int sd = wave * 512;              // wave-uniform LDS dest element (issue 0)
    const int sr = se >> 5;                 // source row within tile
    const int sc = se & 31;                 // source col (k) within tile

    f32x4 acc[4][4] = {};
    const int nt = K >> 5;

    // prologue: stage tile 0 into buffer 0
    gload_lds16(Abase + (long)sr        * lda + sc, &As[0][sd]);
    gload_lds16(Abase + (long)(sr + 64) * lda + sc, &As[0][sd + 2048]);
    gload_lds16(Bbase + (long)sr        * K   + sc, &Bs[0][sd]);
    gload_lds16(Bbase + (long)(sr + 64) * K   + sc, &Bs[0][sd + 2048]);
    __syncthreads();

    int cur = 0;
    for (int t = 0; t < nt; ++t) {
        if (t + 1 < nt) {
            const int kb = (t + 1) << 5;
            gload_lds16(Abase + (long)sr        * lda + kb + sc, &As[cur^1][sd]);
            gload_lds16(Abase + (long)(sr + 64) * lda + kb + sc, &As[cur^1][sd + 2048]);
            gload_lds16(Bbase + (long)sr        * K   + kb + sc, &Bs[cur^1][sd]);
            gload_lds16(Bbase + (long)(sr + 64) * K   + kb + sc, &Bs[cur^1][sd + 2048]);
        }
        bf16x8 a[4], b[4];
        #pragma unroll
        for (int m = 0; m < 4; ++m)
            a[m] = *(const bf16x8*)&As[cur][(wr + m*16 + lr) * 32 + lk];
        #pragma unroll
        for (int n = 0; n < 4; ++n)
            b[n] = *(const bf16x8*)&Bs[cur][(wc + n*16 + lr) * 32 + lk];
        #pragma unroll
        for (int m = 0; m < 4; ++m)
            #pragma unroll
            for (int n = 0; n < 4; ++n)
                acc[m][n] = __builtin_amdgcn_mfma_f32_16x16x32_bf16(a[m], b[n], acc[m][n], 0, 0, 0);
        __syncthreads();
        cur ^= 1;
    }

    // epilogue: C/D layout col = lane&15, row = (lane>>4)*4 + reg
    const int lg = lane >> 4;
    #pragma unroll
    for (int m = 0; m < 4; ++m) {
        #pragma unroll
        for (int n = 0; n < 4; ++n) {
            f32x4 v = acc[m][n];
            #pragma unroll
            for (int r = 0; r < 4; ++r) {
                long row = rowBase + wr + m*16 + lg*4 + r;
                long col = colBase + wc + n*16 + lr;
                long off = row * N + col;
                if (EPI == 0)      ((bf16*)C)[off] = (bf16)v[r];
                else if (EPI == 1) ((bf16*)C)[off] = (bf16)fmaxf(v[r], 0.f);
                else               ((float*)C)[off] = res[off] + v[r];
            }
        }
    }
}

extern "C" void kernel_launch(void* const* d_in, const int* in_sizes, int n_in,
                              void* d_out, int out_size, void* d_ws, size_t ws_size,
                              hipStream_t stream) {
    const float* x      = (const float*)d_in[0];
    const float* W_in   = (const float*)d_in[1];
    const float* cw     = (const float*)d_in[2];
    const float* cb     = (const float*)d_in[3];
    const float* W_out  = (const float*)d_in[4];
    const float* W_mlp1 = (const float*)d_in[5];
    const float* W_mlp2 = (const float*)d_in[6];
    float* out = (float*)d_out;

    char* ws  = (char*)d_ws;
    bf16* wW  = (bf16*)(ws);                    // 33.55 MB (max bf16 weight)
    bf16* h   = (bf16*)(ws + 33554432);         // 33.55 MB (h / h2)
    bf16* xz  = (bf16*)(ws + 67108864);         // 134.2 MB (xz / m1)
    float* x2 = (float*)(ws + 201326592);       // 67.1 MB
    bf16* y   = xz + D_INNER;                   // in-place over z half, lda = 8192
    bf16* m1  = xz;

    dim3 blk(256);

    // mamba branch
    f2b_kernel<<<dim3(8192), blk, 0, stream>>>(W_in, wW, 16777216/8);
    rmsnorm_kernel<<<dim3(ROWS), blk, 0, stream>>>(x, h);
    gemm_bt<0><<<dim3(64, 64), blk, 0, stream>>>(h, D_MODEL, wW, xz, nullptr, 2*D_INNER, D_MODEL);
    conv_gate_kernel<<<dim3(16384), blk, 0, stream>>>(xz, cw, cb);
    f2b_kernel<<<dim3(4096), blk, 0, stream>>>(W_out, wW, 8388608/8);
    gemm_bt<2><<<dim3(16, 64), blk, 0, stream>>>(y, 2*D_INNER, wW, x2, x, D_MODEL, D_INNER);

    // mlp branch
    rmsnorm_kernel<<<dim3(ROWS), blk, 0, stream>>>(x2, h);
    f2b_kernel<<<dim3(8192), blk, 0, stream>>>(W_mlp1, wW, 16777216/8);
    gemm_bt<1><<<dim3(64, 64), blk, 0, stream>>>(h, D_MODEL, wW, m1, nullptr, 4*D_MODEL, D_MODEL);
    f2b_kernel<<<dim3(8192), blk, 0, stream>>>(W_mlp2, wW, 16777216/8);
    gemm_bt<2><<<dim3(16, 64), blk, 0, stream>>>(m1, 4*D_MODEL, wW, out, x2, D_MODEL, 4*D_MODEL);
}

// Round 2
// 1398.491 us; speedup vs baseline: 1.0326x; 1.0326x over previous
//
#include <hip/hip_runtime.h>
#include <hip/hip_bf16.h>

typedef __bf16 bf16;
typedef __bf16 bf16x8 __attribute__((ext_vector_type(8)));
typedef float f32x4 __attribute__((ext_vector_type(4)));

#define D_MODEL 2048
#define D_INNER 4096
#define ROWS    8192   // B*T
#define BM      256

__device__ __forceinline__ void gload_lds16(const void* g, void* l) {
    __builtin_amdgcn_global_load_lds(
        (const __attribute__((address_space(1))) void*)g,
        (__attribute__((address_space(3))) void*)l, 16, 0, 0);
}

// ---------------- fp32 -> bf16 weight convert ----------------
__global__ __launch_bounds__(256) void f2b_kernel(const float* __restrict__ in,
                                                  bf16* __restrict__ out, int n8) {
    int i = blockIdx.x * 256 + threadIdx.x;
    if (i >= n8) return;
    long base = (long)i * 8;
    float4 a = *(const float4*)(in + base);
    float4 b = *(const float4*)(in + base + 4);
    bf16x8 o;
    o[0] = (bf16)a.x; o[1] = (bf16)a.y; o[2] = (bf16)a.z; o[3] = (bf16)a.w;
    o[4] = (bf16)b.x; o[5] = (bf16)b.y; o[6] = (bf16)b.z; o[7] = (bf16)b.w;
    *(bf16x8*)(out + base) = o;
}

// ---------------- rmsnorm (F.normalize * sqrt(D)) fp32 -> bf16 ----------------
__global__ __launch_bounds__(256) void rmsnorm_kernel(const float* __restrict__ x,
                                                      bf16* __restrict__ h) {
    const long row = blockIdx.x;
    const float* xr = x + row * D_MODEL;
    float4 v0 = ((const float4*)xr)[threadIdx.x * 2];
    float4 v1 = ((const float4*)xr)[threadIdx.x * 2 + 1];
    float ss = v0.x*v0.x + v0.y*v0.y + v0.z*v0.z + v0.w*v0.w
             + v1.x*v1.x + v1.y*v1.y + v1.z*v1.z + v1.w*v1.w;
    #pragma unroll
    for (int o = 32; o; o >>= 1) ss += __shfl_xor(ss, o, 64);
    __shared__ float red[4];
    if ((threadIdx.x & 63) == 0) red[threadIdx.x >> 6] = ss;
    __syncthreads();
    float tot = red[0] + red[1] + red[2] + red[3];
    float scale = 45.254834f / fmaxf(sqrtf(tot), 1e-12f);  // sqrt(2048)/max(||x||,eps)
    bf16x8 o;
    o[0] = (bf16)(v0.x*scale); o[1] = (bf16)(v0.y*scale);
    o[2] = (bf16)(v0.z*scale); o[3] = (bf16)(v0.w*scale);
    o[4] = (bf16)(v1.x*scale); o[5] = (bf16)(v1.y*scale);
    o[6] = (bf16)(v1.z*scale); o[7] = (bf16)(v1.w*scale);
    *(bf16x8*)(h + row * D_MODEL + threadIdx.x * 8) = o;
}

// ---------------- depthwise causal conv (4 taps) + SiLU gate ----------------
__global__ __launch_bounds__(256) void conv_gate_kernel(bf16* __restrict__ xz,
                                                        const float* __restrict__ cw,
                                                        const float* __restrict__ cb) {
    const int idx = blockIdx.x * 256 + threadIdx.x;   // ROWS*512 threads
    const int c8  = idx & 511;
    const int row = idx >> 9;
    const int t   = row & 2047;                        // position within batch (T=2048)
    const int c0  = c8 * 8;
    float acc[8];
    float wv[8][4];
    #pragma unroll
    for (int e = 0; e < 8; ++e) {
        float4 f = ((const float4*)cw)[c0 + e];
        wv[e][0] = f.x; wv[e][1] = f.y; wv[e][2] = f.z; wv[e][3] = f.w;
        acc[e] = cb[c0 + e];
    }
    #pragma unroll
    for (int j = 0; j < 4; ++j) {
        if (t + j - 3 >= 0) {
            bf16x8 xv = *(const bf16x8*)(xz + (long)(row + j - 3) * (2*D_INNER) + c0);
            #pragma unroll
            for (int e = 0; e < 8; ++e) acc[e] += (float)xv[e] * wv[e][j];
        }
    }
    bf16* zp = xz + (long)row * (2*D_INNER) + D_INNER + c0;
    bf16x8 zv = *(const bf16x8*)zp;
    bf16x8 yv;
    #pragma unroll
    for (int e = 0; e < 8; ++e) {
        float xc = acc[e];
        float s1 = xc / (1.f + __expf(-xc));
        float z  = (float)zv[e];
        float s2 = z / (1.f + __expf(-z));
        yv[e] = (bf16)(s1 * s2);
    }
    *(bf16x8*)zp = yv;
}

// ---------------- bf16 GEMM v2: C = A @ B^T (+ epilogue) ----------------
// 256x256 tile, BK=32, 512 threads = 8 waves (2 M x 4 N), per-wave 128x64
// output (8x4 frags of mfma_f32_16x16x32_bf16). 4 rotating LDS buffers,
// prefetch distance 3, counted s_waitcnt vmcnt(8) + raw s_barrier (never
// drains). T2 XOR swizzle on [256][32] tiles: phys = q ^ (((q>>7)&3)<<4)
// (involution; 16B-granule preserving). global_load_lds writes linearly, so
// the per-lane GLOBAL source is inverse-swizzled and ds_reads apply the same
// XOR (both-sides rule).
// EPI: 0 = store bf16, 1 = relu+store bf16, 2 = fp32 res-add + store fp32
template<int EPI>
__global__ __launch_bounds__(512, 2) void gemm_bt(
        const bf16* __restrict__ A, long lda,
        const bf16* __restrict__ B,
        void* __restrict__ C, const float* __restrict__ res,
        int N, int K, int gx) {
    __shared__ __align__(16) bf16 As[4][BM*32];
    __shared__ __align__(16) bf16 Bs[4][BM*32];
    const int tid  = threadIdx.x;
    const int wid  = tid >> 6;
    const int lane = tid & 63;
    const int lr   = lane & 15;
    const int lgB  = (lane >> 4) * 16;   // k-granule byte offset within 64B row

    // bijective XCD swizzle (all our grids are %8 == 0)
    const int nwg = gridDim.x;
    const int qq  = nwg >> 3;
    const int sw  = (blockIdx.x & 7) * qq + (blockIdx.x >> 3);
    const int bx  = sw % gx, by = sw / gx;
    const long rowBase = (long)by * BM;
    const long colBase = (long)bx * BM;

    // per-thread staging sources (inverse-swizzled global column)
    const int r0 = tid >> 2;                                  // 0..127
    const int cz = (((tid & 3) ^ ((tid >> 3) & 3)) << 4);     // swizzled byte col
    const bf16* sA0 = A + (rowBase + r0) * lda + (cz >> 1);
    const bf16* sA1 = sA0 + 128 * lda;
    const bf16* sB0 = B + (colBase + r0) * (long)K + (cz >> 1);
    const bf16* sB1 = sB0 + 128 * (long)K;
    const int ldsOff = wid * 1024;   // bytes; builtin adds lane*16

    // per-lane fragment LDS byte offsets (swizzled), loop-invariant
    int aOff[8], bOff[4];
    #pragma unroll
    for (int m = 0; m < 8; ++m) {
        int r = (wid >> 2) * 128 + m * 16 + lr;
        aOff[m] = (r * 64 + lgB) ^ (((r >> 1) & 3) << 4);
    }
    #pragma unroll
    for (int n = 0; n < 4; ++n) {
        int r = (wid & 3) * 64 + n * 16 + lr;
        bOff[n] = (r * 64 + lgB) ^ (((r >> 1) & 3) << 4);
    }

    const int nt = K >> 5;
    f32x4 acc[8][4] = {};

    // prologue: stage tiles 0,1,2 into bufs 0,1,2 (12 loads/wave in flight)
    #pragma unroll
    for (int p = 0; p < 3; ++p) {
        gload_lds16(sA0 + p*32, (char*)As[p] + ldsOff);
        gload_lds16(sA1 + p*32, (char*)As[p] + 8192 + ldsOff);
        gload_lds16(sB0 + p*32, (char*)Bs[p] + ldsOff);
        gload_lds16(sB1 + p*32, (char*)Bs[p] + 8192 + ldsOff);
    }
    asm volatile("s_waitcnt vmcnt(8)" ::: "memory");   // tile 0 landed
    __builtin_amdgcn_s_barrier();
    __builtin_amdgcn_sched_barrier(0);

    for (int t = 0; t < nt; ++t) {
        // stage tile t+3 into buf (t+3)&3 (== buffer consumed at iter t-1).
        // Tail: clamp source to tile 0 (valid addresses, never read) so the
        // vmcnt accounting stays uniform.
        int t3 = t + 3; if (t3 >= nt) t3 = 0;
        const int pb = (t + 3) & 3;
        gload_lds16(sA0 + t3*32, (char*)As[pb] + ldsOff);
        gload_lds16(sA1 + t3*32, (char*)As[pb] + 8192 + ldsOff);
        gload_lds16(sB0 + t3*32, (char*)Bs[pb] + ldsOff);
        gload_lds16(sB1 + t3*32, (char*)Bs[pb] + 8192 + ldsOff);

        const int cb = t & 3;
        bf16x8 a[8], b[4];
        #pragma unroll
        for (int m = 0; m < 8; ++m)
            a[m] = *(const bf16x8*)((const char*)As[cb] + aOff[m]);
        #pragma unroll
        for (int n = 0; n < 4; ++n)
            b[n] = *(const bf16x8*)((const char*)Bs[cb] + bOff[n]);

        __builtin_amdgcn_s_setprio(1);
        #pragma unroll
        for (int m = 0; m < 8; ++m)
            #pragma unroll
            for (int n = 0; n < 4; ++n)
                acc[m][n] = __builtin_amdgcn_mfma_f32_16x16x32_bf16(a[m], b[n], acc[m][n], 0, 0, 0);
        __builtin_amdgcn_s_setprio(0);

        // counted wait: 12 in flight -> oldest 4 (tile t+1) landed; never 0
        asm volatile("s_waitcnt vmcnt(8)" ::: "memory");
        __builtin_amdgcn_s_barrier();
        __builtin_amdgcn_sched_barrier(0);
    }

    // epilogue: C/D layout col = lane&15, row = (lane>>4)*4 + reg
    const int lg = lane >> 4;
    const long wrow = rowBase + (wid >> 2) * 128;
    const long wcol = colBase + (wid & 3) * 64;
    #pragma unroll
    for (int m = 0; m < 8; ++m) {
        #pragma unroll
        for (int n = 0; n < 4; ++n) {
            f32x4 v = acc[m][n];
            #pragma unroll
            for (int r = 0; r < 4; ++r) {
                long row = wrow + m*16 + lg*4 + r;
                long col = wcol + n*16 + lr;
                long off = row * N + col;
                if (EPI == 0)      ((bf16*)C)[off] = (bf16)v[r];
                else if (EPI == 1) ((bf16*)C)[off] = (bf16)fmaxf(v[r], 0.f);
                else               ((float*)C)[off] = res[off] + v[r];
            }
        }
    }
}

extern "C" void kernel_launch(void* const* d_in, const int* in_sizes, int n_in,
                              void* d_out, int out_size, void* d_ws, size_t ws_size,
                              hipStream_t stream) {
    const float* x      = (const float*)d_in[0];
    const float* W_in   = (const float*)d_in[1];
    const float* cw     = (const float*)d_in[2];
    const float* cb     = (const float*)d_in[3];
    const float* W_out  = (const float*)d_in[4];
    const float* W_mlp1 = (const float*)d_in[5];
    const float* W_mlp2 = (const float*)d_in[6];
    float* out = (float*)d_out;

    char* ws  = (char*)d_ws;
    bf16* wW  = (bf16*)(ws);                    // 33.55 MB (max bf16 weight)
    bf16* h   = (bf16*)(ws + 33554432);         // 33.55 MB (h / h2)
    bf16* xz  = (bf16*)(ws + 67108864);         // 134.2 MB (xz / m1)
    float* x2 = (float*)(ws + 201326592);       // 67.1 MB
    bf16* y   = xz + D_INNER;                   // in-place over z half, lda = 8192
    bf16* m1  = xz;

    dim3 blk(256);
    dim3 gblk(512);

    // mamba branch
    f2b_kernel<<<dim3(8192), blk, 0, stream>>>(W_in, wW, 16777216/8);
    rmsnorm_kernel<<<dim3(ROWS), blk, 0, stream>>>(x, h);
    gemm_bt<0><<<dim3(1024), gblk, 0, stream>>>(h, D_MODEL, wW, xz, nullptr, 2*D_INNER, D_MODEL, 32);
    conv_gate_kernel<<<dim3(16384), blk, 0, stream>>>(xz, cw, cb);
    f2b_kernel<<<dim3(4096), blk, 0, stream>>>(W_out, wW, 8388608/8);
    gemm_bt<2><<<dim3(256), gblk, 0, stream>>>(y, 2*D_INNER, wW, x2, x, D_MODEL, D_INNER, 8);

    // mlp branch
    rmsnorm_kernel<<<dim3(ROWS), blk, 0, stream>>>(x2, h);
    f2b_kernel<<<dim3(8192), blk, 0, stream>>>(W_mlp1, wW, 16777216/8);
    gemm_bt<1><<<dim3(1024), gblk, 0, stream>>>(h, D_MODEL, wW, m1, nullptr, 4*D_MODEL, D_MODEL, 32);
    f2b_kernel<<<dim3(8192), blk, 0, stream>>>(W_mlp2, wW, 16777216/8);
    gemm_bt<2><<<dim3(256), gblk, 0, stream>>>(m1, 4*D_MODEL, wW, out, x2, D_MODEL, 4*D_MODEL, 8);
}

// Round 3
// 1341.823 us; speedup vs baseline: 1.0762x; 1.0422x over previous
//
#include <hip/hip_runtime.h>
#include <hip/hip_bf16.h>

typedef __bf16 bf16;
typedef __bf16 bf16x8 __attribute__((ext_vector_type(8)));
typedef float f32x4 __attribute__((ext_vector_type(4)));

#define D_MODEL 2048
#define D_INNER 4096
#define ROWS    8192   // B*T
#define BM      256

__device__ __forceinline__ void gload_lds16(const void* g, void* l) {
    __builtin_amdgcn_global_load_lds(
        (const __attribute__((address_space(1))) void*)g,
        (__attribute__((address_space(3))) void*)l, 16, 0, 0);
}

// ---------------- fp32 -> bf16 weight convert ----------------
__global__ __launch_bounds__(256) void f2b_kernel(const float* __restrict__ in,
                                                  bf16* __restrict__ out, int n8) {
    int i = blockIdx.x * 256 + threadIdx.x;
    if (i >= n8) return;
    long base = (long)i * 8;
    float4 a = *(const float4*)(in + base);
    float4 b = *(const float4*)(in + base + 4);
    bf16x8 o;
    o[0] = (bf16)a.x; o[1] = (bf16)a.y; o[2] = (bf16)a.z; o[3] = (bf16)a.w;
    o[4] = (bf16)b.x; o[5] = (bf16)b.y; o[6] = (bf16)b.z; o[7] = (bf16)b.w;
    *(bf16x8*)(out + base) = o;
}

// ---------------- rmsnorm (F.normalize * sqrt(D)) fp32 -> bf16 ----------------
__global__ __launch_bounds__(256) void rmsnorm_kernel(const float* __restrict__ x,
                                                      bf16* __restrict__ h) {
    const long row = blockIdx.x;
    const float* xr = x + row * D_MODEL;
    float4 v0 = ((const float4*)xr)[threadIdx.x * 2];
    float4 v1 = ((const float4*)xr)[threadIdx.x * 2 + 1];
    float ss = v0.x*v0.x + v0.y*v0.y + v0.z*v0.z + v0.w*v0.w
             + v1.x*v1.x + v1.y*v1.y + v1.z*v1.z + v1.w*v1.w;
    #pragma unroll
    for (int o = 32; o; o >>= 1) ss += __shfl_xor(ss, o, 64);
    __shared__ float red[4];
    if ((threadIdx.x & 63) == 0) red[threadIdx.x >> 6] = ss;
    __syncthreads();
    float tot = red[0] + red[1] + red[2] + red[3];
    float scale = 45.254834f / fmaxf(sqrtf(tot), 1e-12f);  // sqrt(2048)/max(||x||,eps)
    bf16x8 o;
    o[0] = (bf16)(v0.x*scale); o[1] = (bf16)(v0.y*scale);
    o[2] = (bf16)(v0.z*scale); o[3] = (bf16)(v0.w*scale);
    o[4] = (bf16)(v1.x*scale); o[5] = (bf16)(v1.y*scale);
    o[6] = (bf16)(v1.z*scale); o[7] = (bf16)(v1.w*scale);
    *(bf16x8*)(h + row * D_MODEL + threadIdx.x * 8) = o;
}

// ---------------- depthwise causal conv (4 taps) + SiLU gate ----------------
__global__ __launch_bounds__(256) void conv_gate_kernel(bf16* __restrict__ xz,
                                                        const float* __restrict__ cw,
                                                        const float* __restrict__ cb) {
    const int idx = blockIdx.x * 256 + threadIdx.x;   // ROWS*512 threads
    const int c8  = idx & 511;
    const int row = idx >> 9;
    const int t   = row & 2047;                        // position within batch (T=2048)
    const int c0  = c8 * 8;
    float acc[8];
    float wv[8][4];
    #pragma unroll
    for (int e = 0; e < 8; ++e) {
        float4 f = ((const float4*)cw)[c0 + e];
        wv[e][0] = f.x; wv[e][1] = f.y; wv[e][2] = f.z; wv[e][3] = f.w;
        acc[e] = cb[c0 + e];
    }
    #pragma unroll
    for (int j = 0; j < 4; ++j) {
        if (t + j - 3 >= 0) {
            bf16x8 xv = *(const bf16x8*)(xz + (long)(row + j - 3) * (2*D_INNER) + c0);
            #pragma unroll
            for (int e = 0; e < 8; ++e) acc[e] += (float)xv[e] * wv[e][j];
        }
    }
    bf16* zp = xz + (long)row * (2*D_INNER) + D_INNER + c0;
    bf16x8 zv = *(const bf16x8*)zp;
    bf16x8 yv;
    #pragma unroll
    for (int e = 0; e < 8; ++e) {
        float xc = acc[e];
        float s1 = xc / (1.f + __expf(-xc));
        float z  = (float)zv[e];
        float s2 = z / (1.f + __expf(-z));
        yv[e] = (bf16)(s1 * s2);
    }
    *(bf16x8*)zp = yv;
}

// ---------------- bf16 GEMM v3: C = A @ B^T (+ epilogue) ----------------
// 256x256 tile, BK=32, 512 threads = 8 waves (2 M x 4 N), per-wave 128x64.
// 4 rotating LDS buffers, prefetch distance 3, counted vmcnt(8), T2 XOR
// swizzle (phys = q ^ (((q>>7)&3)<<4)), T1 XCD swizzle, T5 setprio.
// NEW (T3): each K-step split into 2 phases of 16 MFMA with the m201
// per-phase interleave: {ds_read subtile, 2 x global_load_lds, s_barrier,
// lgkmcnt(0)+sched_barrier, setprio(1), 16 MFMA, setprio(0), s_barrier}.
// Phase 1: m0-3 x all n (reads 4 A + 4 B frags, stages next A-tile);
// phase 2: m4-7 x all n (reads 4 A frags, reuses B regs, stages next B-tile,
// single counted vmcnt(8) before the closing barrier -- never drains to 0).
// Race proof unchanged from v2: buffer (t+3)&3 was fully consumed at iter
// t-1 (>=2 barriers before the stage issue); vmcnt(8) at end of iter t
// retires all loads through iter t-2 == tile t+1's 4 loads.
// EPI: 0 = store bf16, 1 = relu+store bf16, 2 = fp32 res-add + store fp32
template<int EPI>
__global__ __launch_bounds__(512, 2) void gemm_bt(
        const bf16* __restrict__ A, long lda,
        const bf16* __restrict__ B,
        void* __restrict__ C, const float* __restrict__ res,
        int N, int K, int gx) {
    __shared__ __align__(16) bf16 As[4][BM*32];
    __shared__ __align__(16) bf16 Bs[4][BM*32];
    const int tid  = threadIdx.x;
    const int wid  = tid >> 6;
    const int lane = tid & 63;
    const int lr   = lane & 15;
    const int lgB  = (lane >> 4) * 16;   // k-granule byte offset within 64B row

    // bijective XCD swizzle (all our grids are %8 == 0)
    const int nwg = gridDim.x;
    const int qq  = nwg >> 3;
    const int sw  = (blockIdx.x & 7) * qq + (blockIdx.x >> 3);
    const int bx  = sw % gx, by = sw / gx;
    const long rowBase = (long)by * BM;
    const long colBase = (long)bx * BM;

    // per-thread staging sources (inverse-swizzled global column)
    const int r0 = tid >> 2;                                  // 0..127
    const int cz = (((tid & 3) ^ ((tid >> 3) & 3)) << 4);     // swizzled byte col
    const bf16* sA0 = A + (rowBase + r0) * lda + (cz >> 1);
    const bf16* sA1 = sA0 + 128 * lda;
    const bf16* sB0 = B + (colBase + r0) * (long)K + (cz >> 1);
    const bf16* sB1 = sB0 + 128 * (long)K;
    const int ldsOff = wid * 1024;   // bytes; builtin adds lane*16

    // per-lane fragment LDS byte offsets (swizzled), loop-invariant
    int aOff[8], bOff[4];
    #pragma unroll
    for (int m = 0; m < 8; ++m) {
        int r = (wid >> 2) * 128 + m * 16 + lr;
        aOff[m] = (r * 64 + lgB) ^ (((r >> 1) & 3) << 4);
    }
    #pragma unroll
    for (int n = 0; n < 4; ++n) {
        int r = (wid & 3) * 64 + n * 16 + lr;
        bOff[n] = (r * 64 + lgB) ^ (((r >> 1) & 3) << 4);
    }

    const int nt = K >> 5;
    f32x4 acc[8][4] = {};

    // prologue: stage tiles 0,1,2 into bufs 0,1,2 (12 loads/wave in flight)
    #pragma unroll
    for (int p = 0; p < 3; ++p) {
        gload_lds16(sA0 + p*32, (char*)As[p] + ldsOff);
        gload_lds16(sA1 + p*32, (char*)As[p] + 8192 + ldsOff);
        gload_lds16(sB0 + p*32, (char*)Bs[p] + ldsOff);
        gload_lds16(sB1 + p*32, (char*)Bs[p] + 8192 + ldsOff);
    }
    asm volatile("s_waitcnt vmcnt(8)" ::: "memory");   // tile 0 landed
    __builtin_amdgcn_s_barrier();
    __builtin_amdgcn_sched_barrier(0);

    for (int t = 0; t < nt; ++t) {
        // Tail: clamp prefetch source to tile 0 (valid addrs, never read)
        int t3 = t + 3; if (t3 >= nt) t3 = 0;
        const int pb = (t + 3) & 3;
        const int cb = t & 3;
        const char* Ab = (const char*)As[cb];
        const char* Bb = (const char*)Bs[cb];
        bf16x8 a0[4], a1[4], b[4];

        // ---------- phase 1: m0-3 ----------
        #pragma unroll
        for (int m = 0; m < 4; ++m) a0[m] = *(const bf16x8*)(Ab + aOff[m]);
        #pragma unroll
        for (int n = 0; n < 4; ++n) b[n]  = *(const bf16x8*)(Bb + bOff[n]);
        gload_lds16(sA0 + t3*32, (char*)As[pb] + ldsOff);
        gload_lds16(sA1 + t3*32, (char*)As[pb] + 8192 + ldsOff);
        __builtin_amdgcn_s_barrier();
        asm volatile("s_waitcnt lgkmcnt(0)" ::: "memory");
        __builtin_amdgcn_sched_barrier(0);
        __builtin_amdgcn_s_setprio(1);
        #pragma unroll
        for (int m = 0; m < 4; ++m)
            #pragma unroll
            for (int n = 0; n < 4; ++n)
                acc[m][n] = __builtin_amdgcn_mfma_f32_16x16x32_bf16(a0[m], b[n], acc[m][n], 0, 0, 0);
        __builtin_amdgcn_s_setprio(0);
        __builtin_amdgcn_s_barrier();

        // ---------- phase 2: m4-7 (reuse b regs) ----------
        #pragma unroll
        for (int m = 0; m < 4; ++m) a1[m] = *(const bf16x8*)(Ab + aOff[m + 4]);
        gload_lds16(sB0 + t3*32, (char*)Bs[pb] + ldsOff);
        gload_lds16(sB1 + t3*32, (char*)Bs[pb] + 8192 + ldsOff);
        __builtin_amdgcn_s_barrier();
        asm volatile("s_waitcnt lgkmcnt(0)" ::: "memory");
        __builtin_amdgcn_sched_barrier(0);
        __builtin_amdgcn_s_setprio(1);
        #pragma unroll
        for (int m = 0; m < 4; ++m)
            #pragma unroll
            for (int n = 0; n < 4; ++n)
                acc[m + 4][n] = __builtin_amdgcn_mfma_f32_16x16x32_bf16(a1[m], b[n], acc[m + 4][n], 0, 0, 0);
        __builtin_amdgcn_s_setprio(0);
        // counted wait: 12 in flight -> retire through iter t-2 (tile t+1)
        asm volatile("s_waitcnt vmcnt(8)" ::: "memory");
        __builtin_amdgcn_s_barrier();
        __builtin_amdgcn_sched_barrier(0);
    }

    // epilogue: C/D layout col = lane&15, row = (lane>>4)*4 + reg
    const int lg = lane >> 4;
    const long wrow = rowBase + (wid >> 2) * 128;
    const long wcol = colBase + (wid & 3) * 64;
    #pragma unroll
    for (int m = 0; m < 8; ++m) {
        #pragma unroll
        for (int n = 0; n < 4; ++n) {
            f32x4 v = acc[m][n];
            #pragma unroll
            for (int r = 0; r < 4; ++r) {
                long row = wrow + m*16 + lg*4 + r;
                long col = wcol + n*16 + lr;
                long off = row * N + col;
                if (EPI == 0)      ((bf16*)C)[off] = (bf16)v[r];
                else if (EPI == 1) ((bf16*)C)[off] = (bf16)fmaxf(v[r], 0.f);
                else               ((float*)C)[off] = res[off] + v[r];
            }
        }
    }
}

extern "C" void kernel_launch(void* const* d_in, const int* in_sizes, int n_in,
                              void* d_out, int out_size, void* d_ws, size_t ws_size,
                              hipStream_t stream) {
    const float* x      = (const float*)d_in[0];
    const float* W_in   = (const float*)d_in[1];
    const float* cw     = (const float*)d_in[2];
    const float* cb     = (const float*)d_in[3];
    const float* W_out  = (const float*)d_in[4];
    const float* W_mlp1 = (const float*)d_in[5];
    const float* W_mlp2 = (const float*)d_in[6];
    float* out = (float*)d_out;

    char* ws  = (char*)d_ws;
    bf16* wW  = (bf16*)(ws);                    // 33.55 MB (max bf16 weight)
    bf16* h   = (bf16*)(ws + 33554432);         // 33.55 MB (h / h2)
    bf16* xz  = (bf16*)(ws + 67108864);         // 134.2 MB (xz / m1)
    float* x2 = (float*)(ws + 201326592);       // 67.1 MB
    bf16* y   = xz + D_INNER;                   // in-place over z half, lda = 8192
    bf16* m1  = xz;

    dim3 blk(256);
    dim3 gblk(512);

    // mamba branch
    f2b_kernel<<<dim3(8192), blk, 0, stream>>>(W_in, wW, 16777216/8);
    rmsnorm_kernel<<<dim3(ROWS), blk, 0, stream>>>(x, h);
    gemm_bt<0><<<dim3(1024), gblk, 0, stream>>>(h, D_MODEL, wW, xz, nullptr, 2*D_INNER, D_MODEL, 32);
    conv_gate_kernel<<<dim3(16384), blk, 0, stream>>>(xz, cw, cb);
    f2b_kernel<<<dim3(4096), blk, 0, stream>>>(W_out, wW, 8388608/8);
    gemm_bt<2><<<dim3(256), gblk, 0, stream>>>(y, 2*D_INNER, wW, x2, x, D_MODEL, D_INNER, 8);

    // mlp branch
    rmsnorm_kernel<<<dim3(ROWS), blk, 0, stream>>>(x2, h);
    f2b_kernel<<<dim3(8192), blk, 0, stream>>>(W_mlp1, wW, 16777216/8);
    gemm_bt<1><<<dim3(1024), gblk, 0, stream>>>(h, D_MODEL, wW, m1, nullptr, 4*D_MODEL, D_MODEL, 32);
    f2b_kernel<<<dim3(8192), blk, 0, stream>>>(W_mlp2, wW, 16777216/8);
    gemm_bt<2><<<dim3(256), gblk, 0, stream>>>(m1, 4*D_MODEL, wW, out, x2, D_MODEL, 4*D_MODEL, 8);
}

// Round 4
// 1055.486 us; speedup vs baseline: 1.3682x; 1.2713x over previous
//
#include <hip/hip_runtime.h>
#include <hip/hip_bf16.h>

typedef __bf16 bf16;
typedef __bf16 bf16x8 __attribute__((ext_vector_type(8)));
typedef float f32x4 __attribute__((ext_vector_type(4)));

#define D_MODEL 2048
#define D_INNER 4096
#define ROWS    8192   // B*T

__device__ __forceinline__ void gload_lds16(const void* g, void* l) {
    __builtin_amdgcn_global_load_lds(
        (const __attribute__((address_space(1))) void*)g,
        (__attribute__((address_space(3))) void*)l, 16, 0, 0);
}

// ---------------- fp32 -> bf16 weight convert ----------------
__global__ __launch_bounds__(256) void f2b_kernel(const float* __restrict__ in,
                                                  bf16* __restrict__ out, int n8) {
    int i = blockIdx.x * 256 + threadIdx.x;
    if (i >= n8) return;
    long base = (long)i * 8;
    float4 a = *(const float4*)(in + base);
    float4 b = *(const float4*)(in + base + 4);
    bf16x8 o;
    o[0] = (bf16)a.x; o[1] = (bf16)a.y; o[2] = (bf16)a.z; o[3] = (bf16)a.w;
    o[4] = (bf16)b.x; o[5] = (bf16)b.y; o[6] = (bf16)b.z; o[7] = (bf16)b.w;
    *(bf16x8*)(out + base) = o;
}

// ---------------- rmsnorm (F.normalize * sqrt(D)) fp32 -> bf16 ----------------
__global__ __launch_bounds__(256) void rmsnorm_kernel(const float* __restrict__ x,
                                                      bf16* __restrict__ h) {
    const long row = blockIdx.x;
    const float* xr = x + row * D_MODEL;
    float4 v0 = ((const float4*)xr)[threadIdx.x * 2];
    float4 v1 = ((const float4*)xr)[threadIdx.x * 2 + 1];
    float ss = v0.x*v0.x + v0.y*v0.y + v0.z*v0.z + v0.w*v0.w
             + v1.x*v1.x + v1.y*v1.y + v1.z*v1.z + v1.w*v1.w;
    #pragma unroll
    for (int o = 32; o; o >>= 1) ss += __shfl_xor(ss, o, 64);
    __shared__ float red[4];
    if ((threadIdx.x & 63) == 0) red[threadIdx.x >> 6] = ss;
    __syncthreads();
    float tot = red[0] + red[1] + red[2] + red[3];
    float scale = 45.254834f / fmaxf(sqrtf(tot), 1e-12f);  // sqrt(2048)/max(||x||,eps)
    bf16x8 o;
    o[0] = (bf16)(v0.x*scale); o[1] = (bf16)(v0.y*scale);
    o[2] = (bf16)(v0.z*scale); o[3] = (bf16)(v0.w*scale);
    o[4] = (bf16)(v1.x*scale); o[5] = (bf16)(v1.y*scale);
    o[6] = (bf16)(v1.z*scale); o[7] = (bf16)(v1.w*scale);
    *(bf16x8*)(h + row * D_MODEL + threadIdx.x * 8) = o;
}

// ---------------- depthwise causal conv (4 taps) + SiLU gate ----------------
__global__ __launch_bounds__(256) void conv_gate_kernel(bf16* __restrict__ xz,
                                                        const float* __restrict__ cw,
                                                        const float* __restrict__ cb) {
    const int idx = blockIdx.x * 256 + threadIdx.x;   // ROWS*512 threads
    const int c8  = idx & 511;
    const int row = idx >> 9;
    const int t   = row & 2047;                        // position within batch (T=2048)
    const int c0  = c8 * 8;
    float acc[8];
    float wv[8][4];
    #pragma unroll
    for (int e = 0; e < 8; ++e) {
        float4 f = ((const float4*)cw)[c0 + e];
        wv[e][0] = f.x; wv[e][1] = f.y; wv[e][2] = f.z; wv[e][3] = f.w;
        acc[e] = cb[c0 + e];
    }
    #pragma unroll
    for (int j = 0; j < 4; ++j) {
        if (t + j - 3 >= 0) {
            bf16x8 xv = *(const bf16x8*)(xz + (long)(row + j - 3) * (2*D_INNER) + c0);
            #pragma unroll
            for (int e = 0; e < 8; ++e) acc[e] += (float)xv[e] * wv[e][j];
        }
    }
    bf16* zp = xz + (long)row * (2*D_INNER) + D_INNER + c0;
    bf16x8 zv = *(const bf16x8*)zp;
    bf16x8 yv;
    #pragma unroll
    for (int e = 0; e < 8; ++e) {
        float xc = acc[e];
        float s1 = xc / (1.f + __expf(-xc));
        float z  = (float)zv[e];
        float s2 = z / (1.f + __expf(-z));
        yv[e] = (bf16)(s1 * s2);
    }
    *(bf16x8*)zp = yv;
}

// ---------------- bf16 GEMM v4 (m201-faithful): C = A @ B^T ----------------
// 256x256 tile, BK=64, 512 threads = 8 waves (2M x 4N), per-wave 128x64.
// LDS: 2 dbuf x [A:2x16KB halves | B:2x16KB halves] = 128 KiB. Each half is
// [128 rows][64 bf16] with 8-chunk XOR swizzle: chunk' = chunk ^ (row&7)
// (16B chunks; 2 lanes/bank = free). global_load_lds writes linearly, so the
// per-lane GLOBAL source column is inverse-swizzled: chunk = (l&7)^((l>>3)&7).
// K-tile = 4 phases = C-quadrants (m0n0, m0n1, m1n1, m1n0), 16 MFMA each;
// A/B frags reused across adjacent phases (24 ds_read_b128 per K-tile).
// Stage placement from last-read analysis: B halves last read in ph2 ->
// staged ph3; A halves last read in ph3 -> staged ph4. One counted vmcnt(8)
// per K-tile at ph4 (16 in flight -> retires exactly tile t+1); never 0 in
// the main loop. Tail stages clamp to k-tile 0 (valid addrs, never read);
// vmcnt(0) before epilogue so no LDS-DMA outlives the block.
// EPI: 0 = store bf16, 1 = relu+store bf16, 2 = fp32 res-add + store fp32
template<int EPI>
__global__ __launch_bounds__(512, 2) void gemm_bt(
        const bf16* __restrict__ A, long lda,
        const bf16* __restrict__ B,
        void* __restrict__ C, const float* __restrict__ res,
        int N, int K, int gx) {
    __shared__ __align__(16) char LB[131072];
    const int tid = threadIdx.x;
    const int w   = tid >> 6;
    const int l   = tid & 63;
    const int lr  = l & 15;

    // bijective XCD swizzle (all grids %8 == 0)
    const int nwg = gridDim.x;
    const int qq  = nwg >> 3;
    const int sw  = (blockIdx.x & 7) * qq + (blockIdx.x >> 3);
    const int bx  = sw % gx, by = sw / gx;
    const long rowBase = (long)by * 256;
    const long colBase = (long)bx * 256;

    // staging sources: thread covers row (w*8 + l>>3), 16B chunk (l&7)^((l>>3)&7)
    const int srow = w * 8 + (l >> 3);
    const int schk = (l & 7) ^ ((l >> 3) & 7);
    const bf16* aSrc = A + (rowBase + srow) * lda + schk * 8;
    const bf16* bSrc = B + (colBase + srow) * (long)K + schk * 8;
    const long lda64 = 64 * lda;
    const long ldb64 = 64 * (long)K;
    const int  w1024 = w * 1024;

    auto stgA = [&](int DBB, int kt) {   // A halves -> dbuf DBB (4 loads)
        const bf16* s = aSrc + (long)kt * 64;
        gload_lds16(s,            LB + DBB +     0 + w1024);
        gload_lds16(s +   lda64,  LB + DBB +  8192 + w1024);
        gload_lds16(s + 2*lda64,  LB + DBB + 16384 + w1024);
        gload_lds16(s + 3*lda64,  LB + DBB + 24576 + w1024);
    };
    auto stgB = [&](int DBB, int kt) {   // B halves -> dbuf DBB (4 loads)
        const bf16* s = bSrc + (long)kt * 64;
        gload_lds16(s,            LB + DBB + 32768 + w1024);
        gload_lds16(s +   ldb64,  LB + DBB + 40960 + w1024);
        gload_lds16(s + 2*ldb64,  LB + DBB + 49152 + w1024);
        gload_lds16(s + 3*ldb64,  LB + DBB + 57344 + w1024);
    };

    // fragment read offsets (swizzled); row&7 == l&7 for all frag rows
    const int cx0 = (((l >> 4)    ) ^ (l & 7)) << 4;
    const int cx1 = (((l >> 4) + 4) ^ (l & 7)) << 4;
    const int hm = w >> 2;     // A half (M)
    const int q  = w & 3;      // B quarter (N)
    int aRow[8], bRow[4];
    #pragma unroll
    for (int m = 0; m < 8; ++m) aRow[m] = hm * 16384 + (m * 16 + lr) * 128;
    #pragma unroll
    for (int n = 0; n < 4; ++n)
        bRow[n] = 32768 + (q >> 1) * 16384 + ((q & 1) * 64 + n * 16 + lr) * 128;

    const int nt  = K >> 6;
    const int nit = nt >> 1;
    f32x4 acc[8][4] = {};

    // prologue: stage tile0 -> dbuf0, tile1 -> dbuf1 (16 loads in flight)
    stgA(0, 0); stgB(0, 0);
    stgA(65536, 1); stgB(65536, 1);
    asm volatile("s_waitcnt vmcnt(8)" ::: "memory");   // tile 0 landed
    __builtin_amdgcn_s_barrier();
    __builtin_amdgcn_sched_barrier(0);

    for (int it = 0; it < nit; ++it) {
        int kA = 2 * it + 2; if (kA >= nt) kA = 0;     // dummy clamp in tail
        int kB = 2 * it + 3; if (kB >= nt) kB = 0;
        #pragma unroll
        for (int db = 0; db < 2; ++db) {
            const int DBB = db * 65536;
            const int kst = db ? kB : kA;
            const char* Lb = LB + DBB;
            bf16x8 aR[4][2], bL[2][2], bH[2][2];

            // ---- ph1: read A(m0) 8 + B(n0) 4; MFMA q(m0,n0) ----
            #pragma unroll
            for (int m = 0; m < 4; ++m) {
                aR[m][0] = *(const bf16x8*)(Lb + aRow[m] + cx0);
                aR[m][1] = *(const bf16x8*)(Lb + aRow[m] + cx1);
            }
            #pragma unroll
            for (int n = 0; n < 2; ++n) {
                bL[n][0] = *(const bf16x8*)(Lb + bRow[n] + cx0);
                bL[n][1] = *(const bf16x8*)(Lb + bRow[n] + cx1);
            }
            __builtin_amdgcn_s_barrier();
            asm volatile("s_waitcnt lgkmcnt(0)" ::: "memory");
            __builtin_amdgcn_sched_barrier(0);
            __builtin_amdgcn_s_setprio(1);
            #pragma unroll
            for (int m = 0; m < 4; ++m)
                #pragma unroll
                for (int n = 0; n < 2; ++n) {
                    acc[m][n] = __builtin_amdgcn_mfma_f32_16x16x32_bf16(aR[m][0], bL[n][0], acc[m][n], 0, 0, 0);
                    acc[m][n] = __builtin_amdgcn_mfma_f32_16x16x32_bf16(aR[m][1], bL[n][1], acc[m][n], 0, 0, 0);
                }
            __builtin_amdgcn_s_setprio(0);
            __builtin_amdgcn_s_barrier();

            // ---- ph2: read B(n1) 4; MFMA q(m0,n1) ----
            #pragma unroll
            for (int n = 0; n < 2; ++n) {
                bH[n][0] = *(const bf16x8*)(Lb + bRow[n + 2] + cx0);
                bH[n][1] = *(const bf16x8*)(Lb + bRow[n + 2] + cx1);
            }
            __builtin_amdgcn_s_barrier();
            asm volatile("s_waitcnt lgkmcnt(0)" ::: "memory");
            __builtin_amdgcn_sched_barrier(0);
            __builtin_amdgcn_s_setprio(1);
            #pragma unroll
            for (int m = 0; m < 4; ++m)
                #pragma unroll
                for (int n = 0; n < 2; ++n) {
                    acc[m][n + 2] = __builtin_amdgcn_mfma_f32_16x16x32_bf16(aR[m][0], bH[n][0], acc[m][n + 2], 0, 0, 0);
                    acc[m][n + 2] = __builtin_amdgcn_mfma_f32_16x16x32_bf16(aR[m][1], bH[n][1], acc[m][n + 2], 0, 0, 0);
                }
            __builtin_amdgcn_s_setprio(0);
            __builtin_amdgcn_s_barrier();

            // ---- ph3: read A(m1) 8; stage B(t+2); MFMA q(m1,n1) ----
            #pragma unroll
            for (int m = 0; m < 4; ++m) {
                aR[m][0] = *(const bf16x8*)(Lb + aRow[m + 4] + cx0);
                aR[m][1] = *(const bf16x8*)(Lb + aRow[m + 4] + cx1);
            }
            stgB(DBB, kst);
            __builtin_amdgcn_s_barrier();
            asm volatile("s_waitcnt lgkmcnt(0)" ::: "memory");
            __builtin_amdgcn_sched_barrier(0);
            __builtin_amdgcn_s_setprio(1);
            #pragma unroll
            for (int m = 0; m < 4; ++m)
                #pragma unroll
                for (int n = 0; n < 2; ++n) {
                    acc[m + 4][n + 2] = __builtin_amdgcn_mfma_f32_16x16x32_bf16(aR[m][0], bH[n][0], acc[m + 4][n + 2], 0, 0, 0);
                    acc[m + 4][n + 2] = __builtin_amdgcn_mfma_f32_16x16x32_bf16(aR[m][1], bH[n][1], acc[m + 4][n + 2], 0, 0, 0);
                }
            __builtin_amdgcn_s_setprio(0);
            __builtin_amdgcn_s_barrier();

            // ---- ph4: stage A(t+2); MFMA q(m1,n0); counted vmcnt ----
            stgA(DBB, kst);
            __builtin_amdgcn_s_barrier();
            __builtin_amdgcn_s_setprio(1);
            #pragma unroll
            for (int m = 0; m < 4; ++m)
                #pragma unroll
                for (int n = 0; n < 2; ++n) {
                    acc[m + 4][n] = __builtin_amdgcn_mfma_f32_16x16x32_bf16(aR[m][0], bL[n][0], acc[m + 4][n], 0, 0, 0);
                    acc[m + 4][n] = __builtin_amdgcn_mfma_f32_16x16x32_bf16(aR[m][1], bL[n][1], acc[m + 4][n], 0, 0, 0);
                }
            __builtin_amdgcn_s_setprio(0);
            asm volatile("s_waitcnt vmcnt(8)" ::: "memory");   // tile t+1 landed
            __builtin_amdgcn_s_barrier();
        }
    }

    // drain dummy prefetch DMAs before the block can exit
    asm volatile("s_waitcnt vmcnt(0)" ::: "memory");

    // epilogue: C/D layout col = lane&15, row = (lane>>4)*4 + reg
    const int lg = l >> 4;
    const long wrow = rowBase + hm * 128;
    const long wcol = colBase + q * 64;
    #pragma unroll
    for (int m = 0; m < 8; ++m) {
        #pragma unroll
        for (int n = 0; n < 4; ++n) {
            f32x4 v = acc[m][n];
            #pragma unroll
            for (int r = 0; r < 4; ++r) {
                long row = wrow + m*16 + lg*4 + r;
                long col = wcol + n*16 + lr;
                long off = row * N + col;
                if (EPI == 0)      ((bf16*)C)[off] = (bf16)v[r];
                else if (EPI == 1) ((bf16*)C)[off] = (bf16)fmaxf(v[r], 0.f);
                else               ((float*)C)[off] = res[off] + v[r];
            }
        }
    }
}

extern "C" void kernel_launch(void* const* d_in, const int* in_sizes, int n_in,
                              void* d_out, int out_size, void* d_ws, size_t ws_size,
                              hipStream_t stream) {
    const float* x      = (const float*)d_in[0];
    const float* W_in   = (const float*)d_in[1];
    const float* cw     = (const float*)d_in[2];
    const float* cb     = (const float*)d_in[3];
    const float* W_out  = (const float*)d_in[4];
    const float* W_mlp1 = (const float*)d_in[5];
    const float* W_mlp2 = (const float*)d_in[6];
    float* out = (float*)d_out;

    char* ws  = (char*)d_ws;
    bf16* wW  = (bf16*)(ws);                    // 33.55 MB (max bf16 weight)
    bf16* h   = (bf16*)(ws + 33554432);         // 33.55 MB (h / h2)
    bf16* xz  = (bf16*)(ws + 67108864);         // 134.2 MB (xz / m1)
    float* x2 = (float*)(ws + 201326592);       // 67.1 MB
    bf16* y   = xz + D_INNER;                   // in-place over z half, lda = 8192
    bf16* m1  = xz;

    dim3 blk(256);
    dim3 gblk(512);

    // mamba branch
    f2b_kernel<<<dim3(8192), blk, 0, stream>>>(W_in, wW, 16777216/8);
    rmsnorm_kernel<<<dim3(ROWS), blk, 0, stream>>>(x, h);
    gemm_bt<0><<<dim3(1024), gblk, 0, stream>>>(h, D_MODEL, wW, xz, nullptr, 2*D_INNER, D_MODEL, 32);
    conv_gate_kernel<<<dim3(16384), blk, 0, stream>>>(xz, cw, cb);
    f2b_kernel<<<dim3(4096), blk, 0, stream>>>(W_out, wW, 8388608/8);
    gemm_bt<2><<<dim3(256), gblk, 0, stream>>>(y, 2*D_INNER, wW, x2, x, D_MODEL, D_INNER, 8);

    // mlp branch
    rmsnorm_kernel<<<dim3(ROWS), blk, 0, stream>>>(x2, h);
    f2b_kernel<<<dim3(8192), blk, 0, stream>>>(W_mlp1, wW, 16777216/8);
    gemm_bt<1><<<dim3(1024), gblk, 0, stream>>>(h, D_MODEL, wW, m1, nullptr, 4*D_MODEL, D_MODEL, 32);
    f2b_kernel<<<dim3(8192), blk, 0, stream>>>(W_mlp2, wW, 16777216/8);
    gemm_bt<2><<<dim3(256), gblk, 0, stream>>>(m1, 4*D_MODEL, wW, out, x2, D_MODEL, 4*D_MODEL, 8);
}

// Round 5
// 1006.848 us; speedup vs baseline: 1.4343x; 1.0483x over previous
//
#include <hip/hip_runtime.h>
#include <hip/hip_bf16.h>

typedef __bf16 bf16;
typedef __bf16 bf16x8 __attribute__((ext_vector_type(8)));
typedef float f32x4 __attribute__((ext_vector_type(4)));

#define D_MODEL 2048
#define D_INNER 4096
#define ROWS    8192   // B*T

__device__ __forceinline__ void gload_lds16(const void* g, void* l) {
    __builtin_amdgcn_global_load_lds(
        (const __attribute__((address_space(1))) void*)g,
        (__attribute__((address_space(3))) void*)l, 16, 0, 0);
}

// ---------------- fp32 -> bf16 weight convert ----------------
__global__ __launch_bounds__(256) void f2b_kernel(const float* __restrict__ in,
                                                  bf16* __restrict__ out, int n8) {
    int i = blockIdx.x * 256 + threadIdx.x;
    if (i >= n8) return;
    long base = (long)i * 8;
    float4 a = *(const float4*)(in + base);
    float4 b = *(const float4*)(in + base + 4);
    bf16x8 o;
    o[0] = (bf16)a.x; o[1] = (bf16)a.y; o[2] = (bf16)a.z; o[3] = (bf16)a.w;
    o[4] = (bf16)b.x; o[5] = (bf16)b.y; o[6] = (bf16)b.z; o[7] = (bf16)b.w;
    *(bf16x8*)(out + base) = o;
}

// ---------------- rmsnorm (F.normalize * sqrt(D)) fp32 -> bf16 ----------------
__global__ __launch_bounds__(256) void rmsnorm_kernel(const float* __restrict__ x,
                                                      bf16* __restrict__ h) {
    const long row = blockIdx.x;
    const float* xr = x + row * D_MODEL;
    float4 v0 = ((const float4*)xr)[threadIdx.x * 2];
    float4 v1 = ((const float4*)xr)[threadIdx.x * 2 + 1];
    float ss = v0.x*v0.x + v0.y*v0.y + v0.z*v0.z + v0.w*v0.w
             + v1.x*v1.x + v1.y*v1.y + v1.z*v1.z + v1.w*v1.w;
    #pragma unroll
    for (int o = 32; o; o >>= 1) ss += __shfl_xor(ss, o, 64);
    __shared__ float red[4];
    if ((threadIdx.x & 63) == 0) red[threadIdx.x >> 6] = ss;
    __syncthreads();
    float tot = red[0] + red[1] + red[2] + red[3];
    float scale = 45.254834f / fmaxf(sqrtf(tot), 1e-12f);  // sqrt(2048)/max(||x||,eps)
    bf16x8 o;
    o[0] = (bf16)(v0.x*scale); o[1] = (bf16)(v0.y*scale);
    o[2] = (bf16)(v0.z*scale); o[3] = (bf16)(v0.w*scale);
    o[4] = (bf16)(v1.x*scale); o[5] = (bf16)(v1.y*scale);
    o[6] = (bf16)(v1.z*scale); o[7] = (bf16)(v1.w*scale);
    *(bf16x8*)(h + row * D_MODEL + threadIdx.x * 8) = o;
}

// ---------------- depthwise causal conv (4 taps) + SiLU gate ----------------
__global__ __launch_bounds__(256) void conv_gate_kernel(bf16* __restrict__ xz,
                                                        const float* __restrict__ cw,
                                                        const float* __restrict__ cb) {
    const int idx = blockIdx.x * 256 + threadIdx.x;   // ROWS*512 threads
    const int c8  = idx & 511;
    const int row = idx >> 9;
    const int t   = row & 2047;                        // position within batch (T=2048)
    const int c0  = c8 * 8;
    float acc[8];
    float wv[8][4];
    #pragma unroll
    for (int e = 0; e < 8; ++e) {
        float4 f = ((const float4*)cw)[c0 + e];
        wv[e][0] = f.x; wv[e][1] = f.y; wv[e][2] = f.z; wv[e][3] = f.w;
        acc[e] = cb[c0 + e];
    }
    #pragma unroll
    for (int j = 0; j < 4; ++j) {
        if (t + j - 3 >= 0) {
            bf16x8 xv = *(const bf16x8*)(xz + (long)(row + j - 3) * (2*D_INNER) + c0);
            #pragma unroll
            for (int e = 0; e < 8; ++e) acc[e] += (float)xv[e] * wv[e][j];
        }
    }
    bf16* zp = xz + (long)row * (2*D_INNER) + D_INNER + c0;
    bf16x8 zv = *(const bf16x8*)zp;
    bf16x8 yv;
    #pragma unroll
    for (int e = 0; e < 8; ++e) {
        float xc = acc[e];
        float s1 = xc / (1.f + __expf(-xc));
        float z  = (float)zv[e];
        float s2 = z / (1.f + __expf(-z));
        yv[e] = (bf16)(s1 * s2);
    }
    *(bf16x8*)zp = yv;
}

// ---------------- bf16 GEMM v5 (pipelined reads): C = A @ B^T ----------------
// 256x256 tile, BK=64, 512 threads = 8 waves (2M x 4N), per-wave 128x64.
// Same LDS layout/swizzle/staging as v4 (2 dbuf x 64KB, XOR chunk swizzle,
// inverse-swizzled global source). NEW: 2 super-phases per K-tile with every
// ds_read block issued while the previous quadrant's MFMAs run, reusing frag
// registers (AX holds A0 then A1; BL/BH persistent) so VGPR stays ~124.
//   P_A(t): stageB(t+2) | q2=A0xBH | vmcnt(4) | read A1->AX | lgkm |
//           q3=A1xBH | barrier
//   P_B(t): q4=A1xBL | stageA(t+2) | read A0,B0,B1(t+1) from other dbuf |
//           lgkm | q1(t+1)=A0xBL | barrier      (q1 skipped on last tile)
// Safety ledger: staged region's readers lgkm'd >=1 barrier before the stage
// issues (B read in P_B(t-1) < bar < stgB; A1 read in P_A(t) < bar(P_A) <
// stgA in P_B). Reads of staged data are >=1 barrier after all waves'
// covering vmcnt: vmcnt(4) in P_A(t) leaves only B(t+2) outstanding (FIFO)
// => A(t+1)/B(t+1) landed; the t+1 reads happen after bar(P_A). vmcnt never
// drains in the loop; vmcnt(0) before exit so no DMA outlives the block.
// EPI: 0 = store bf16, 1 = relu+store bf16, 2 = fp32 res-add + store fp32
template<int EPI>
__global__ __launch_bounds__(512, 2) void gemm_bt(
        const bf16* __restrict__ A, long lda,
        const bf16* __restrict__ B,
        void* __restrict__ C, const float* __restrict__ res,
        int N, int K, int gx) {
    __shared__ __align__(16) char LB[131072];
    const int tid = threadIdx.x;
    const int w   = tid >> 6;
    const int l   = tid & 63;
    const int lr  = l & 15;

    // bijective XCD swizzle (all grids %8 == 0)
    const int nwg = gridDim.x;
    const int qq  = nwg >> 3;
    const int sw  = (blockIdx.x & 7) * qq + (blockIdx.x >> 3);
    const int bx  = sw % gx, by = sw / gx;
    const long rowBase = (long)by * 256;
    const long colBase = (long)bx * 256;

    // staging sources: thread covers row (w*8 + l>>3), 16B chunk (l&7)^((l>>3)&7)
    const int srow = w * 8 + (l >> 3);
    const int schk = (l & 7) ^ ((l >> 3) & 7);
    const bf16* aSrc = A + (rowBase + srow) * lda + schk * 8;
    const bf16* bSrc = B + (colBase + srow) * (long)K + schk * 8;
    const long lda64 = 64 * lda;
    const long ldb64 = 64 * (long)K;
    const int  w1024 = w * 1024;

    auto stgA = [&](int DBB, int kt) {   // A halves -> dbuf DBB (4 loads)
        const bf16* s = aSrc + (long)kt * 64;
        gload_lds16(s,            LB + DBB +     0 + w1024);
        gload_lds16(s +   lda64,  LB + DBB +  8192 + w1024);
        gload_lds16(s + 2*lda64,  LB + DBB + 16384 + w1024);
        gload_lds16(s + 3*lda64,  LB + DBB + 24576 + w1024);
    };
    auto stgB = [&](int DBB, int kt) {   // B halves -> dbuf DBB (4 loads)
        const bf16* s = bSrc + (long)kt * 64;
        gload_lds16(s,            LB + DBB + 32768 + w1024);
        gload_lds16(s +   ldb64,  LB + DBB + 40960 + w1024);
        gload_lds16(s + 2*ldb64,  LB + DBB + 49152 + w1024);
        gload_lds16(s + 3*ldb64,  LB + DBB + 57344 + w1024);
    };

    // fragment read offsets (swizzled); row&7 == l&7 for all frag rows
    const int cx0 = (((l >> 4)    ) ^ (l & 7)) << 4;
    const int cx1 = (((l >> 4) + 4) ^ (l & 7)) << 4;
    const int hm = w >> 2;     // A half (M)
    const int q  = w & 3;      // B quarter (N)
    int aRow[8], bRow[4];
    #pragma unroll
    for (int m = 0; m < 8; ++m) aRow[m] = hm * 16384 + (m * 16 + lr) * 128;
    #pragma unroll
    for (int n = 0; n < 4; ++n)
        bRow[n] = 32768 + (q >> 1) * 16384 + ((q & 1) * 64 + n * 16 + lr) * 128;

    const int nt  = K >> 6;
    const int nit = nt >> 1;
    f32x4 acc[8][4] = {};
    bf16x8 AX[4][2], BL[2][2], BH[2][2];

    // prologue: stage tile0 -> dbuf0, tile1 -> dbuf1 (B then A per tile)
    stgB(0, 0);      stgA(0, 0);
    stgB(65536, 1);  stgA(65536, 1);
    asm volatile("s_waitcnt vmcnt(8)" ::: "memory");   // tile 0 landed
    __builtin_amdgcn_s_barrier();
    __builtin_amdgcn_sched_barrier(0);
    // read tile0 q1-frags: AX=A0, BL=B0, BH=B1 (16 reads)
    #pragma unroll
    for (int m = 0; m < 4; ++m) {
        AX[m][0] = *(const bf16x8*)(LB + aRow[m] + cx0);
        AX[m][1] = *(const bf16x8*)(LB + aRow[m] + cx1);
    }
    #pragma unroll
    for (int n = 0; n < 2; ++n) {
        BL[n][0] = *(const bf16x8*)(LB + bRow[n]     + cx0);
        BL[n][1] = *(const bf16x8*)(LB + bRow[n]     + cx1);
        BH[n][0] = *(const bf16x8*)(LB + bRow[n + 2] + cx0);
        BH[n][1] = *(const bf16x8*)(LB + bRow[n + 2] + cx1);
    }
    asm volatile("s_waitcnt lgkmcnt(0)" ::: "memory");
    __builtin_amdgcn_sched_barrier(0);
    __builtin_amdgcn_s_setprio(1);
    #pragma unroll
    for (int m = 0; m < 4; ++m)
        #pragma unroll
        for (int n = 0; n < 2; ++n) {
            acc[m][n] = __builtin_amdgcn_mfma_f32_16x16x32_bf16(AX[m][0], BL[n][0], acc[m][n], 0, 0, 0);
            acc[m][n] = __builtin_amdgcn_mfma_f32_16x16x32_bf16(AX[m][1], BL[n][1], acc[m][n], 0, 0, 0);
        }
    __builtin_amdgcn_s_setprio(0);
    __builtin_amdgcn_s_barrier();

    for (int it = 0; it < nit; ++it) {
        int kA = 2 * it + 2; if (kA >= nt) kA = 0;     // dummy clamp in tail
        int kB = 2 * it + 3; if (kB >= nt) kB = 0;
        #pragma unroll
        for (int db = 0; db < 2; ++db) {
            const int DBB = db * 65536;
            const char* Lb = LB + DBB;
            const char* Ln = LB + (DBB ^ 65536);
            const int kst = db ? kB : kA;
            const bool full = (db == 0) || (it < nit - 1);

            // ================= P_A =================
            stgB(DBB, kst);
            __builtin_amdgcn_s_setprio(1);
            #pragma unroll
            for (int m = 0; m < 4; ++m)                       // q2: A0 x B1
                #pragma unroll
                for (int n = 0; n < 2; ++n) {
                    acc[m][n + 2] = __builtin_amdgcn_mfma_f32_16x16x32_bf16(AX[m][0], BH[n][0], acc[m][n + 2], 0, 0, 0);
                    acc[m][n + 2] = __builtin_amdgcn_mfma_f32_16x16x32_bf16(AX[m][1], BH[n][1], acc[m][n + 2], 0, 0, 0);
                }
            __builtin_amdgcn_s_setprio(0);
            asm volatile("s_waitcnt vmcnt(4)" ::: "memory");   // t+1 landed (FIFO)
            __builtin_amdgcn_sched_barrier(0);
            #pragma unroll
            for (int m = 0; m < 4; ++m) {                      // AX <- A1(t)
                AX[m][0] = *(const bf16x8*)(Lb + aRow[m + 4] + cx0);
                AX[m][1] = *(const bf16x8*)(Lb + aRow[m + 4] + cx1);
            }
            asm volatile("s_waitcnt lgkmcnt(0)" ::: "memory");
            __builtin_amdgcn_sched_barrier(0);
            __builtin_amdgcn_s_setprio(1);
            #pragma unroll
            for (int m = 0; m < 4; ++m)                       // q3: A1 x B1
                #pragma unroll
                for (int n = 0; n < 2; ++n) {
                    acc[m + 4][n + 2] = __builtin_amdgcn_mfma_f32_16x16x32_bf16(AX[m][0], BH[n][0], acc[m + 4][n + 2], 0, 0, 0);
                    acc[m + 4][n + 2] = __builtin_amdgcn_mfma_f32_16x16x32_bf16(AX[m][1], BH[n][1], acc[m + 4][n + 2], 0, 0, 0);
                }
            __builtin_amdgcn_s_setprio(0);
            __builtin_amdgcn_s_barrier();

            // ================= P_B =================
            __builtin_amdgcn_s_setprio(1);
            #pragma unroll
            for (int m = 0; m < 4; ++m)                       // q4: A1 x B0(old)
                #pragma unroll
                for (int n = 0; n < 2; ++n) {
                    acc[m + 4][n] = __builtin_amdgcn_mfma_f32_16x16x32_bf16(AX[m][0], BL[n][0], acc[m + 4][n], 0, 0, 0);
                    acc[m + 4][n] = __builtin_amdgcn_mfma_f32_16x16x32_bf16(AX[m][1], BL[n][1], acc[m + 4][n], 0, 0, 0);
                }
            __builtin_amdgcn_s_setprio(0);
            __builtin_amdgcn_sched_barrier(0);
            stgA(DBB, kst);
            if (full) {
                // read next tile's q1-frags from the other dbuf
                #pragma unroll
                for (int m = 0; m < 4; ++m) {                  // AX <- A0(t+1)
                    AX[m][0] = *(const bf16x8*)(Ln + aRow[m] + cx0);
                    AX[m][1] = *(const bf16x8*)(Ln + aRow[m] + cx1);
                }
                #pragma unroll
                for (int n = 0; n < 2; ++n) {                  // BL/BH <- B(t+1)
                    BL[n][0] = *(const bf16x8*)(Ln + bRow[n]     + cx0);
                    BL[n][1] = *(const bf16x8*)(Ln + bRow[n]     + cx1);
                    BH[n][0] = *(const bf16x8*)(Ln + bRow[n + 2] + cx0);
                    BH[n][1] = *(const bf16x8*)(Ln + bRow[n + 2] + cx1);
                }
                asm volatile("s_waitcnt lgkmcnt(0)" ::: "memory");
                __builtin_amdgcn_sched_barrier(0);
                __builtin_amdgcn_s_setprio(1);
                #pragma unroll
                for (int m = 0; m < 4; ++m)                   // q1(t+1): A0 x B0
                    #pragma unroll
                    for (int n = 0; n < 2; ++n) {
                        acc[m][n] = __builtin_amdgcn_mfma_f32_16x16x32_bf16(AX[m][0], BL[n][0], acc[m][n], 0, 0, 0);
                        acc[m][n] = __builtin_amdgcn_mfma_f32_16x16x32_bf16(AX[m][1], BL[n][1], acc[m][n], 0, 0, 0);
                    }
                __builtin_amdgcn_s_setprio(0);
            }
            __builtin_amdgcn_s_barrier();
        }
    }

    // drain dummy prefetch DMAs before the block can exit
    asm volatile("s_waitcnt vmcnt(0)" ::: "memory");

    // epilogue: C/D layout col = lane&15, row = (lane>>4)*4 + reg
    const int lg = l >> 4;
    const long wrow = rowBase + hm * 128;
    const long wcol = colBase + q * 64;
    #pragma unroll
    for (int m = 0; m < 8; ++m) {
        #pragma unroll
        for (int n = 0; n < 4; ++n) {
            f32x4 v = acc[m][n];
            #pragma unroll
            for (int r = 0; r < 4; ++r) {
                long row = wrow + m*16 + lg*4 + r;
                long col = wcol + n*16 + lr;
                long off = row * N + col;
                if (EPI == 0)      ((bf16*)C)[off] = (bf16)v[r];
                else if (EPI == 1) ((bf16*)C)[off] = (bf16)fmaxf(v[r], 0.f);
                else               ((float*)C)[off] = res[off] + v[r];
            }
        }
    }
}

extern "C" void kernel_launch(void* const* d_in, const int* in_sizes, int n_in,
                              void* d_out, int out_size, void* d_ws, size_t ws_size,
                              hipStream_t stream) {
    const float* x      = (const float*)d_in[0];
    const float* W_in   = (const float*)d_in[1];
    const float* cw     = (const float*)d_in[2];
    const float* cb     = (const float*)d_in[3];
    const float* W_out  = (const float*)d_in[4];
    const float* W_mlp1 = (const float*)d_in[5];
    const float* W_mlp2 = (const float*)d_in[6];
    float* out = (float*)d_out;

    char* ws  = (char*)d_ws;
    bf16* wW  = (bf16*)(ws);                    // 33.55 MB (max bf16 weight)
    bf16* h   = (bf16*)(ws + 33554432);         // 33.55 MB (h / h2)
    bf16* xz  = (bf16*)(ws + 67108864);         // 134.2 MB (xz / m1)
    float* x2 = (float*)(ws + 201326592);       // 67.1 MB
    bf16* y   = xz + D_INNER;                   // in-place over z half, lda = 8192
    bf16* m1  = xz;

    dim3 blk(256);
    dim3 gblk(512);

    // mamba branch
    f2b_kernel<<<dim3(8192), blk, 0, stream>>>(W_in, wW, 16777216/8);
    rmsnorm_kernel<<<dim3(ROWS), blk, 0, stream>>>(x, h);
    gemm_bt<0><<<dim3(1024), gblk, 0, stream>>>(h, D_MODEL, wW, xz, nullptr, 2*D_INNER, D_MODEL, 32);
    conv_gate_kernel<<<dim3(16384), blk, 0, stream>>>(xz, cw, cb);
    f2b_kernel<<<dim3(4096), blk, 0, stream>>>(W_out, wW, 8388608/8);
    gemm_bt<2><<<dim3(256), gblk, 0, stream>>>(y, 2*D_INNER, wW, x2, x, D_MODEL, D_INNER, 8);

    // mlp branch
    rmsnorm_kernel<<<dim3(ROWS), blk, 0, stream>>>(x2, h);
    f2b_kernel<<<dim3(8192), blk, 0, stream>>>(W_mlp1, wW, 16777216/8);
    gemm_bt<1><<<dim3(1024), gblk, 0, stream>>>(h, D_MODEL, wW, m1, nullptr, 4*D_MODEL, D_MODEL, 32);
    f2b_kernel<<<dim3(8192), blk, 0, stream>>>(W_mlp2, wW, 16777216/8);
    gemm_bt<2><<<dim3(256), gblk, 0, stream>>>(m1, 4*D_MODEL, wW, out, x2, D_MODEL, 4*D_MODEL, 8);
}